// Round 11
// baseline (20695.601 us; speedup 1.0000x reference)
//
#include <hip/hip_runtime.h>

#define HS   512
#define LNUM 4
#define TT   128
#define MMEM 2048
#define FFD  2048
#define NB   256
#define NT   512
#define INV512 (1.0f/512.0f)
#define QSCALE 0.08838834764831845f  // 1/sqrt(128)
#define NWIN  659                    // 5*128 + 6*3 + 1

typedef unsigned short ushortt;

// ---------------- workspace layout (float offsets) ----------------
constexpr size_t KHALF  = (size_t)LNUM*MMEM*HS/2;
constexpr size_t HHALF  = (size_t)LNUM*HS*HS/2;
constexpr size_t FHALF  = (size_t)LNUM*FFD*HS/2;
constexpr size_t GHALF  = (size_t)LNUM*3*HS*HS/2;
constexpr size_t OFF_KBF    = 0;
constexpr size_t OFF_VBF    = OFF_KBF    + KHALF;
constexpr size_t OFF_WCOMBBF= OFF_VBF    + KHALF;
constexpr size_t OFF_WQTBF  = OFF_WCOMBBF+ HHALF;
constexpr size_t OFF_CAWOBF = OFF_WQTBF  + HHALF;
constexpr size_t OFF_W2TBF  = OFF_CAWOBF + HHALF;
constexpr size_t OFF_FFW1BF = OFF_W2TBF  + FHALF;
constexpr size_t OFF_WGCBF  = OFF_FFW1BF + FHALF;
constexpr size_t OFF_WXBF   = OFF_WGCBF  + FHALF;
constexpr size_t OFF_WHBF   = OFF_WXBF   + GHALF;
constexpr size_t OFF_CSA    = OFF_WHBF   + GHALF;                // L*HS
constexpr size_t OFF_SQ     = OFF_CSA    + (size_t)LNUM*HS;
constexpr size_t OFF_CBQ    = OFF_SQ     + (size_t)LNUM*HS;
constexpr size_t OFF_SU     = OFF_CBQ    + (size_t)LNUM*HS;      // L*FF
constexpr size_t OFF_CF1    = OFF_SU     + (size_t)LNUM*FFD;
constexpr size_t OFF_CF2    = OFF_CF1    + (size_t)LNUM*FFD;
// mutable (memset 0)
constexpr size_t OFF_STATE  = OFF_CF2    + (size_t)LNUM*FFD;
constexpr size_t OFF_HX     = OFF_STATE;                         // [4][512]
constexpr size_t OFF_Z1     = OFF_HX     + 4*HS;                 // [4][512]
constexpr size_t OFF_Z02    = OFF_Z1     + 4*HS;                 // [4][2][1024]
constexpr size_t OFF_T1     = OFF_Z02    + 4*2*2*HS;             // [4][512]
constexpr size_t OFF_T2     = OFF_T1     + 4*HS;                 // [4][512]
constexpr size_t OFF_YP     = OFF_T2     + 4*HS;                 // [4][32][512]
constexpr size_t OFF_CTXP   = OFF_YP     + 4*32*HS;              // [4][32][128]
constexpr size_t OFF_Y2P    = OFF_CTXP   + 4*32*128;             // [4][32][512]
constexpr size_t OFF_DENS   = OFF_Y2P    + 4*32*HS;              // [4][32]
constexpr size_t OFF_S1S    = OFF_DENS   + 4*32;                 // [4][64]
constexpr size_t OFF_S2S    = OFF_S1S    + 4*64;                 // [4][64]
constexpr size_t OFF_FLAGS  = OFF_S2S    + 4*64;                 // NB*32 u32
constexpr size_t WS_TOTAL   = OFF_FLAGS  + (size_t)NB*32;

__device__ __forceinline__ float wred(float v) {
#pragma unroll
  for (int m = 32; m; m >>= 1) v += __shfl_xor(v, m);
  return v;
}
__device__ __forceinline__ float sigm(float x) { return 1.0f/(1.0f+__expf(-x)); }
__device__ __forceinline__ ushortt f2bf(float f) {
  unsigned u = __float_as_uint(f);
  return (ushortt)((u + 0x7fffu + ((u >> 16) & 1u)) >> 16);
}
__device__ __forceinline__ float bflo(unsigned v){ return __uint_as_float(v << 16); }
__device__ __forceinline__ float bfhi(unsigned v){ return __uint_as_float(v & 0xffff0000u); }
__device__ __forceinline__ unsigned ldpack(const ushortt* a, const ushortt* b){
  return (unsigned)(*a) | ((unsigned)(*b) << 16);
}
__device__ __forceinline__ float ald(const float* p) {
  return __hip_atomic_load(p, __ATOMIC_RELAXED, __HIP_MEMORY_SCOPE_AGENT);
}
__device__ __forceinline__ void ast(float* p, float v) {
  __hip_atomic_store(p, v, __ATOMIC_RELAXED, __HIP_MEMORY_SCOPE_AGENT);
}
__device__ __forceinline__ unsigned aldu(const unsigned* p) {
  return __hip_atomic_load(p, __ATOMIC_RELAXED, __HIP_MEMORY_SCOPE_AGENT);
}
__device__ __forceinline__ void astu(unsigned* p, unsigned v) {
  __hip_atomic_store(p, v, __ATOMIC_RELAXED, __HIP_MEMORY_SCOPE_AGENT);
}

// direct-poll grid barrier with prefetch hook overlapping the wait (R6-proven)
template <class F>
__device__ __forceinline__ void gridbar(unsigned* flags, unsigned g, F&& pf) {
  asm volatile("s_waitcnt vmcnt(0)" ::: "memory");
  __syncthreads();
  if (threadIdx.x == 0) astu(flags + (size_t)blockIdx.x*32, g);
  pf();
  if (threadIdx.x < NB) {
    const unsigned* f = flags + (size_t)threadIdx.x*32;
    while ((int)(aldu(f) - g) < 0) __builtin_amdgcn_s_sleep(2);
  }
  __syncthreads();
}

// warp0: reduce 32 (sum,sumsq) slot pairs -> sh[o], sh[o+1]
__device__ __forceinline__ void slotred32(const float* slots, float* sh, int o,
                                          int w, int lane) {
  if (w == 0) {
    float a = (lane < 32) ? ald(slots + lane*2) : ald(slots + (lane-32)*2 + 1);
#pragma unroll
    for (int m = 16; m; m >>= 1) a += __shfl_xor(a, m);
    if (lane == 0)  sh[o]   = a;
    if (lane == 32) sh[o+1] = a;
  }
}

// ---------------- precompute kernels (R6/R8-proven) ----------------

__global__ __launch_bounds__(256) void kv_gemm(
    const float* __restrict__ hist, const float* __restrict__ caWin,
    const float* __restrict__ caBin, ushortt* __restrict__ out, int koff) {
  __shared__ float As[16][64];
  __shared__ float Bs[16][64];
  const int l = blockIdx.z, m0 = blockIdx.x*64, f0 = blockIdx.y*64;
  const int tid = threadIdx.x, tm = tid >> 4, tf = tid & 15;
  float acc[4][4] = {};
  for (int e0 = 0; e0 < HS; e0 += 16) {
#pragma unroll
    for (int it = 0; it < 4; ++it) {
      int idx = tid + it*256, k = idx & 15, mm = idx >> 4;
      As[k][mm] = hist[((size_t)(m0+mm)*LNUM + l)*HS + e0 + k];
      Bs[k][mm] = caWin[((size_t)l*(3*HS) + koff + f0 + mm)*HS + e0 + k];
    }
    __syncthreads();
#pragma unroll
    for (int k = 0; k < 16; ++k) {
      float a[4], b[4];
#pragma unroll
      for (int xx = 0; xx < 4; ++xx) { a[xx] = As[k][tm*4+xx]; b[xx] = Bs[k][tf*4+xx]; }
#pragma unroll
      for (int xx = 0; xx < 4; ++xx)
#pragma unroll
        for (int y = 0; y < 4; ++y) acc[xx][y] += a[xx]*b[y];
    }
    __syncthreads();
  }
#pragma unroll
  for (int xx = 0; xx < 4; ++xx)
#pragma unroll
    for (int y = 0; y < 4; ++y) {
      int m = m0 + tm*4 + xx, f = f0 + tf*4 + y;
      out[((size_t)l*MMEM + m)*HS + f] = f2bf(acc[xx][y] + caBin[l*(3*HS) + koff + f]);
    }
}

__global__ __launch_bounds__(256) void wcomb_gemm(
    const float* __restrict__ saWo, const float* __restrict__ saWin,
    ushortt* __restrict__ wcomb) {
  __shared__ float As[16][64];
  __shared__ float Bs[16][64];
  const int l = blockIdx.z, f0 = blockIdx.x*64, j0 = blockIdx.y*64;
  const int tid = threadIdx.x, tm = tid >> 4, tf = tid & 15;
  float acc[4][4] = {};
  for (int e0 = 0; e0 < HS; e0 += 16) {
#pragma unroll
    for (int it = 0; it < 4; ++it) {
      int idx = tid + it*256;
      { int k = idx & 15, ff = idx >> 4;
        As[k][ff] = saWo[((size_t)l*HS + f0+ff)*HS + e0 + k]; }
      { int jj = idx & 63, k = idx >> 6;
        Bs[k][jj] = saWin[((size_t)l*(3*HS) + 2*HS + e0 + k)*HS + j0 + jj]; }
    }
    __syncthreads();
#pragma unroll
    for (int k = 0; k < 16; ++k) {
      float a[4], b[4];
#pragma unroll
      for (int xx = 0; xx < 4; ++xx) { a[xx] = As[k][tm*4+xx]; b[xx] = Bs[k][tf*4+xx]; }
#pragma unroll
      for (int xx = 0; xx < 4; ++xx)
#pragma unroll
        for (int y = 0; y < 4; ++y) acc[xx][y] += a[xx]*b[y];
    }
    __syncthreads();
  }
#pragma unroll
  for (int xx = 0; xx < 4; ++xx)
#pragma unroll
    for (int y = 0; y < 4; ++y)
      wcomb[(size_t)l*HS*HS + (size_t)(f0+tm*4+xx)*HS + (j0+tf*4+y)] = f2bf(acc[xx][y]);
}

__global__ __launch_bounds__(256) void wgc_gemm(
    const float* __restrict__ ffW1, const float* __restrict__ lnG,
    const float* __restrict__ caWo, ushortt* __restrict__ wgc) {
  __shared__ float As[16][64];
  __shared__ float Bs[16][64];
  const int l = blockIdx.z, f0 = blockIdx.x*64, j0 = blockIdx.y*64;
  const int tid = threadIdx.x, tm = tid >> 4, tf = tid & 15;
  float acc[4][4] = {};
  for (int e0 = 0; e0 < HS; e0 += 16) {
#pragma unroll
    for (int it = 0; it < 4; ++it) {
      int idx = tid + it*256;
      { int k = idx & 15, ff = idx >> 4;
        As[k][ff] = ffW1[((size_t)l*FFD + f0+ff)*HS + e0 + k] * lnG[l*(3*HS) + HS + e0 + k]; }
      { int jj = idx & 63, k = idx >> 6;
        Bs[k][jj] = caWo[((size_t)l*HS + e0 + k)*HS + j0 + jj]; }
    }
    __syncthreads();
#pragma unroll
    for (int k = 0; k < 16; ++k) {
      float a[4], b[4];
#pragma unroll
      for (int xx = 0; xx < 4; ++xx) { a[xx] = As[k][tm*4+xx]; b[xx] = Bs[k][tf*4+xx]; }
#pragma unroll
      for (int xx = 0; xx < 4; ++xx)
#pragma unroll
        for (int y = 0; y < 4; ++y) acc[xx][y] += a[xx]*b[y];
    }
    __syncthreads();
  }
#pragma unroll
  for (int xx = 0; xx < 4; ++xx)
#pragma unroll
    for (int y = 0; y < 4; ++y)
      wgc[(size_t)l*FFD*HS + (size_t)(f0+tm*4+xx)*HS + (j0+tf*4+y)] = f2bf(acc[xx][y]);
}

__global__ __launch_bounds__(256) void transpose_scale_bf(
    const float* __restrict__ in, size_t inLS, int R, int C,
    const float* __restrict__ g, size_t gLS,
    ushortt* __restrict__ out, size_t outLS) {
  __shared__ float tile[32][33];
  const int l = blockIdx.z, e0 = blockIdx.x*32, f0 = blockIdx.y*32;
  const int tx = threadIdx.x & 31, ty = threadIdx.x >> 5;
#pragma unroll
  for (int r = 0; r < 32; r += 8)
    tile[ty+r][tx] = in[(size_t)l*inLS + (size_t)(f0+ty+r)*C + e0 + tx];
  __syncthreads();
#pragma unroll
  for (int r = 0; r < 32; r += 8) {
    int e = e0 + ty + r, f = f0 + tx;
    float s = g ? g[(size_t)l*gLS + e] : 1.0f;
    out[(size_t)l*outLS + (size_t)e*R + f] = f2bf(tile[tx][ty+r] * s);
  }
}

__global__ __launch_bounds__(256) void bf16_copy(
    const float* __restrict__ in, ushortt* __restrict__ out, size_t n) {
  for (size_t i = (size_t)blockIdx.x*256 + threadIdx.x; i < n; i += (size_t)gridDim.x*256)
    out[i] = f2bf(in[i]);
}

__global__ __launch_bounds__(256) void csa_kernel(
    const float* __restrict__ saWo, const float* __restrict__ sabin,
    const float* __restrict__ sabo, float* __restrict__ csa) {
  const int w = threadIdx.x >> 6, lane = threadIdx.x & 63;
  const int row = blockIdx.x*4 + w;
  const int l = row >> 9, f = row & 511;
  float acc = 0;
#pragma unroll
  for (int k = 0; k < 8; ++k) {
    int e = lane + 64*k;
    acc += saWo[((size_t)l*HS + f)*HS + e] * sabin[l*(3*HS) + 2*HS + e];
  }
  acc = wred(acc);
  if (lane == 0) csa[row] = acc + sabo[l*HS + f];
}

__global__ __launch_bounds__(256) void sqcbq_kernel(
    const float* __restrict__ caWin, const float* __restrict__ caBin,
    const float* __restrict__ lnG, const float* __restrict__ lnB,
    float* __restrict__ sq, float* __restrict__ cbq) {
  const int w = threadIdx.x >> 6, lane = threadIdx.x & 63;
  const int row = blockIdx.x*4 + w;
  const int l = row >> 9, f = row & 511;
  float a1 = 0, a2 = 0;
#pragma unroll
  for (int k = 0; k < 8; ++k) {
    int e = lane + 64*k;
    float wv = caWin[((size_t)l*(3*HS) + f)*HS + e];
    a1 += wv * lnG[l*(3*HS) + e];
    a2 += wv * lnB[l*(3*HS) + e];
  }
  a1 = wred(a1); a2 = wred(a2);
  if (lane == 0) { sq[row] = a1; cbq[row] = a2 + caBin[l*(3*HS) + f]; }
}

__global__ __launch_bounds__(256) void ffvec_kernel(
    const float* __restrict__ ffW1, const float* __restrict__ ffB1,
    const float* __restrict__ caBo,
    const float* __restrict__ lnG, const float* __restrict__ lnB,
    float* __restrict__ su, float* __restrict__ c1, float* __restrict__ c2) {
  const int w = threadIdx.x >> 6, lane = threadIdx.x & 63;
  const int row = blockIdx.x*4 + w;
  const int l = row >> 11, k = row & 2047;
  float a1 = 0, a2 = 0, a3 = 0;
#pragma unroll
  for (int q = 0; q < 8; ++q) {
    int e = lane + 64*q;
    float wv = ffW1[((size_t)l*FFD + k)*HS + e];
    float g2 = lnG[l*(3*HS) + HS + e];
    a1 += wv * g2;
    a2 += wv * g2 * caBo[l*HS + e];
    a3 += wv * lnB[l*(3*HS) + HS + e];
  }
  a1 = wred(a1); a2 = wred(a2); a3 = wred(a3);
  if (lane == 0) { su[row] = a1; c1[row] = a2; c2[row] = a3 + ffB1[(size_t)l*FFD + k]; }
}

// ---------------- main wavefront-pipelined persistent kernel ----------------
// 4 groups x 64 blocks; group g owns layer g. Cell (t,i) at windows 5t+6i+{0..4}.
// A = blocks 0-31 (t1/attn/t2); B = 32-63 (update/z-gates/ff).
// pj[48] rolling prefetch (<=192B: under PromoteAlloca limit; R9/R10's 576B spilled).

__global__ __launch_bounds__(NT, 1) void seq_kernel(
    const float* __restrict__ x,
    const float* __restrict__ bx, const float* __restrict__ bh,
    const float* __restrict__ caBo, const float* __restrict__ ffB2,
    const float* __restrict__ lnG,  const float* __restrict__ lnB,
    float* __restrict__ ws, float* __restrict__ out) {
  const int bid = blockIdx.x, tid = threadIdx.x;
  const int w = tid >> 6, lane = tid & 63;
  const int grp = bid >> 6, gb = bid & 63;
  const bool isA = gb < 32;
  const int l = grp;
  const int g4 = tid >> 7, dd = tid & 127;

  const ushortt* Kb  = (const ushortt*)(ws + OFF_KBF)    + (size_t)l*MMEM*HS;
  const ushortt* Vb  = (const ushortt*)(ws + OFF_VBF)    + (size_t)l*MMEM*HS;
  const ushortt* WC  = (const ushortt*)(ws + OFF_WCOMBBF)+ (size_t)l*HS*HS;
  const ushortt* WQ  = (const ushortt*)(ws + OFF_WQTBF)  + (size_t)l*HS*HS;
  const ushortt* CAW = (const ushortt*)(ws + OFF_CAWOBF) + (size_t)l*HS*HS;
  const ushortt* W2  = (const ushortt*)(ws + OFF_W2TBF)  + (size_t)l*FFD*HS;
  const ushortt* F1  = (const ushortt*)(ws + OFF_FFW1BF) + (size_t)l*FFD*HS;
  const ushortt* WG  = (const ushortt*)(ws + OFF_WGCBF)  + (size_t)l*FFD*HS;
  const ushortt* WXb = (const ushortt*)(ws + OFF_WXBF)   + (size_t)l*3*HS*HS;
  const ushortt* WHb = (const ushortt*)(ws + OFF_WHBF)   + (size_t)l*3*HS*HS;
  const float* csag = ws + OFF_CSA + l*HS;
  const float* sqg  = ws + OFF_SQ  + l*HS;
  const float* cbqg = ws + OFF_CBQ + l*HS;
  const float* suv  = ws + OFF_SU  + (size_t)l*FFD;
  const float* cf1  = ws + OFF_CF1 + (size_t)l*FFD;
  const float* cf2  = ws + OFF_CF2 + (size_t)l*FFD;
  float* hXl  = ws + OFF_HX  + l*HS;
  float* hXp  = ws + OFF_HX  + (l-1)*HS;
  float* z1g  = ws + OFF_Z1  + l*HS;
  float* z02g = ws + OFF_Z02 + (size_t)l*2*1024;
  float* t1g  = ws + OFF_T1  + l*HS;
  float* t2g  = ws + OFF_T2  + l*HS;
  float* YP   = ws + OFF_YP  + (size_t)l*32*HS;
  float* CTXP = ws + OFF_CTXP+ (size_t)l*32*128;
  float* Y2P  = ws + OFF_Y2P + (size_t)l*32*HS;
  float* denS = ws + OFF_DENS+ l*32;
  float* s1s  = ws + OFF_S1S + l*64;
  float* s2s  = ws + OFF_S2S + l*64;
  unsigned* bflags = (unsigned*)(ws + OFF_FLAGS);

  __shared__ float sh_xin[HS], sh_h[HS], sh_vec[HS];
  __shared__ float sh_q[128], sh_p[256], sh_t1[16], sh_t2[16];
  __shared__ float sh_u[64], sh_ff[64], sh_red[24], sh_den[4];

  // rolling per-window weight prefetch (<=48 words => promotable)
  unsigned pj[48];

  auto pf = [&](int Wn) {
    const int Vn = Wn - 6*grp;
    if (Vn < 0 || Vn > 640) return;
    const int tn = Vn/5, pn = Vn - tn*5;
    if (tn > 127) return;
    if (isA) {
      const int b = gb, head = b >> 3, mseg = b & 7;
      if (pn == 1) {
#pragma unroll
        for (int rr = 0; rr < 2; ++rr) {
          const ushortt* wc = WC + (size_t)(b*16 + w*2 + rr)*HS;
#pragma unroll
          for (int kk = 0; kk < 4; ++kk)
            pj[rr*4+kk] = ldpack(wc + lane + 128*kk, wc + lane + 64 + 128*kk);
        }
#pragma unroll
        for (int q = 0; q < 8; ++q)
          pj[8+q] = ldpack(WQ + (size_t)(b*16 + 2*q)*HS + tid,
                           WQ + (size_t)(b*16 + 2*q+1)*HS + tid);
      } else if (pn == 2) {
#pragma unroll
        for (int rr = 0; rr < 32; ++rr) {
          const ushortt* kr = Kb + (size_t)(mseg*256 + w*32 + rr)*HS + head*128;
          pj[rr] = ldpack(kr + lane, kr + lane + 64);
        }
      } else if (pn == 3) {
#pragma unroll
        for (int rr = 0; rr < 2; ++rr) {
          const ushortt* ca = CAW + (size_t)(b*16 + w*2 + rr)*HS;
#pragma unroll
          for (int kk = 0; kk < 4; ++kk)
            pj[rr*4+kk] = ldpack(ca + lane + 128*kk, ca + lane + 64 + 128*kk);
        }
      }
    } else {
      const int c = gb - 32;
      if (pn == 0) {
#pragma unroll
        for (int rr = 0; rr < 2; ++rr) {
          const ushortt* zx = WXb + (size_t)(HS + c*16 + w*2 + rr)*HS;
          const ushortt* zh = WHb + (size_t)(HS + c*16 + w*2 + rr)*HS;
#pragma unroll
          for (int kk = 0; kk < 4; ++kk) {
            pj[rr*4+kk]     = ldpack(zx + lane + 128*kk, zx + lane + 64 + 128*kk);
            pj[8 + rr*4+kk] = ldpack(zh + lane + 128*kk, zh + lane + 64 + 128*kk);
          }
        }
#pragma unroll
        for (int rr = 0; rr < 4; ++rr) {
          const int rowid = c*32 + w*4 + rr;
          const int g = (rowid < 512) ? 0 : 2, f = rowid & 511;
          const ushortt* zx = WXb + (size_t)(g*HS + f)*HS;
          const ushortt* zh = WHb + (size_t)(g*HS + f)*HS;
#pragma unroll
          for (int kk = 0; kk < 4; ++kk) {
            pj[16 + rr*4+kk] = ldpack(zx + lane + 128*kk, zx + lane + 64 + 128*kk);
            pj[32 + rr*4+kk] = ldpack(zh + lane + 128*kk, zh + lane + 64 + 128*kk);
          }
        }
      } else if (pn == 3) {
#pragma unroll
        for (int q = 0; q < 8; ++q) {
          const ushortt* b1 = F1 + (size_t)(c*64 + w*8 + q)*HS;
#pragma unroll
          for (int kk = 0; kk < 4; ++kk)
            pj[q*4+kk] = ldpack(b1 + lane + 128*kk, b1 + lane + 64 + 128*kk);
        }
      } else if (pn == 4) {
#pragma unroll
        for (int q = 0; q < 32; ++q)
          pj[q] = ldpack(W2 + (size_t)(c*64 + 2*q)*HS + tid,
                         W2 + (size_t)(c*64 + 2*q+1)*HS + tid);
      }
    }
  };

  float h_reg = 0.f, c_reg = 0.f;

  auto do_update = [&](int tp) {
    const int j = tid, pz = tp & 1;
    float t2v = ald(t2g + j);
    float z0  = ald(z02g + pz*1024 + j);
    float z2  = ald(z02g + pz*1024 + 512 + j);
    float y2 = 0;
    {
      float yv[16];
#pragma unroll
      for (int c = 0; c < 32; c += 16) {
#pragma unroll
        for (int p = 0; p < 16; ++p) yv[p] = ald(Y2P + (size_t)(c+p)*HS + j);
#pragma unroll
        for (int p = 0; p < 16; ++p) y2 += yv[p];
      }
    }
    slotred32(s2s, sh_red, 16, w, lane);
    __syncthreads();
    float m2 = sh_red[16]*INV512;
    float r2 = rsqrtf(sh_red[17]*INV512 - m2*m2 + 1e-5f);
    float x2 = (t2v-m2)*r2*lnG[(l*3+1)*HS+j] + lnB[(l*3+1)*HS+j];
    float t3 = x2 + y2 + ffB2[l*HS + j];
    float s_ = t3, q_ = t3*t3;
#pragma unroll
    for (int m = 32; m; m >>= 1) { s_ += __shfl_xor(s_, m); q_ += __shfl_xor(q_, m); }
    if (lane == 0) { sh_red[w] = s_; sh_red[8+w] = q_; }
    __syncthreads();
    if (tid == 0) {
      float a = 0, b = 0;
#pragma unroll
      for (int k = 0; k < 8; ++k) { a += sh_red[k]; b += sh_red[8+k]; }
      sh_red[0] = a; sh_red[1] = b;
    }
    __syncthreads();
    float m3 = sh_red[0]*INV512;
    float r3 = rsqrtf(sh_red[1]*INV512 - m3*m3 + 1e-5f);
    float d  = (t3-m3)*r3*lnG[(l*3+2)*HS+j] + lnB[(l*3+2)*HS+j];
    float ft = sigm(c_reg - d);
    float it = sigm(z0);
    float gt = tanhf(z2);
    c_reg = ft*c_reg + it*gt;
    h_reg = tanhf(c_reg);
  };

  pf(0);

  for (int W = 0; W < NWIN; ++W) {
    const int V = W - 6*grp;
    if (V >= 0 && V <= 640) {
      const int t = V/5, ph5 = V - t*5;
      if (ph5 == 0 && !isA) {
        const int c = gb - 32;
        if (t > 0) {
          do_update(t-1);
          if (c == 0) {
            ast(hXl + tid, h_reg);
            if (grp == 3) out[(t-1)*HS + tid] = h_reg;
          }
        }
        if (t <= 127) {
          float xin = (grp == 0) ? x[t*HS + tid] : ald(hXp + tid);
          sh_xin[tid] = xin;
          sh_h[tid]   = h_reg;
          __syncthreads();
#pragma unroll
          for (int rr = 0; rr < 2; ++rr) {
            const int row = c*16 + w*2 + rr;
            float acc = 0;
#pragma unroll
            for (int kk = 0; kk < 4; ++kk) {
              unsigned px = pj[rr*4+kk], phh = pj[8+rr*4+kk];
              acc += bflo(px)*sh_xin[lane+128*kk] + bfhi(px)*sh_xin[lane+64+128*kk]
                   + bflo(phh)*sh_h[lane+128*kk] + bfhi(phh)*sh_h[lane+64+128*kk];
            }
            acc = wred(acc);
            if (lane == 0)
              ast(z1g + row, acc + bx[(l*3+1)*HS + row] + bh[(l*3+1)*HS + row]);
          }
#pragma unroll
          for (int rr = 0; rr < 4; ++rr) {
            const int rowid = c*32 + w*4 + rr;
            const int g = (rowid < 512) ? 0 : 2, f = rowid & 511;
            float acc = 0;
#pragma unroll
            for (int kk = 0; kk < 4; ++kk) {
              unsigned px = pj[16+rr*4+kk], phh = pj[32+rr*4+kk];
              acc += bflo(px)*sh_xin[lane+128*kk] + bfhi(px)*sh_xin[lane+64+128*kk]
                   + bflo(phh)*sh_h[lane+128*kk] + bfhi(phh)*sh_h[lane+64+128*kk];
            }
            acc = wred(acc);
            if (lane == 0)
              ast(z02g + (t&1)*1024 + (g ? 512 : 0) + f,
                  acc + bx[(l*3+g)*HS + f] + bh[(l*3+g)*HS + f]);
          }
        } else {
          if (c == 0) {
            out[TT*HS + grp*HS + tid] = h_reg;
            out[TT*HS + LNUM*HS + grp*HS + tid] = c_reg;
            if (grp == 3) out[127*HS + tid] = h_reg;
          }
        }
      } else if (isA && t <= 127) {
        const int b = gb, head = b >> 3, mseg = b & 7;
        if (ph5 == 1) {
          sh_vec[tid] = sigm(ald(z1g + tid));
          __syncthreads();
#pragma unroll
          for (int rr = 0; rr < 2; ++rr) {
            const int r = w*2 + rr, j = b*16 + r;
            float acc = 0;
#pragma unroll
            for (int kk = 0; kk < 4; ++kk) {
              unsigned pw = pj[rr*4+kk];
              acc += bflo(pw)*sh_vec[lane+128*kk] + bfhi(pw)*sh_vec[lane+64+128*kk];
            }
            acc = wred(acc);
            if (lane == 0) {
              float t1v = sh_vec[j] + acc + csag[j];
              sh_t1[r] = t1v;
              ast(t1g + j, t1v);
            }
          }
          __syncthreads();
          {
            float yl = 0;
#pragma unroll
            for (int q = 0; q < 8; ++q) {
              unsigned pw = pj[8+q];
              yl += sh_t1[2*q]*bflo(pw) + sh_t1[2*q+1]*bfhi(pw);
            }
            ast(YP + (size_t)b*HS + tid, yl);
          }
          if (w == 0 && lane < 16) {
            float v = sh_t1[lane], s_ = v, q_ = v*v;
#pragma unroll
            for (int m = 8; m; m >>= 1) { s_ += __shfl_xor(s_, m); q_ += __shfl_xor(q_, m); }
            if (lane == 0) { ast(s1s + b*2, s_); ast(s1s + b*2 + 1, q_); }
          }
        } else if (ph5 == 2) {
          // issue V at-use loads FIRST (independent; latency hides under q/scores)
          unsigned vv[32];
#pragma unroll
          for (int q = 0; q < 32; ++q)
            vv[q] = ldpack(Vb + (size_t)(mseg*256 + g4*64 + 2*q)*HS + head*128 + dd,
                           Vb + (size_t)(mseg*256 + g4*64 + 2*q+1)*HS + head*128 + dd);
          {
            float part = 0;
            float yv[8];
#pragma unroll
            for (int p = 0; p < 8; ++p) yv[p] = ald(YP + (size_t)(g4*8+p)*HS + head*128 + dd);
#pragma unroll
            for (int p = 0; p < 8; ++p) part += yv[p];
            sh_vec[tid] = part;
          }
          slotred32(s1s, sh_red, 18, w, lane);
          __syncthreads();
          if (tid < 128) {
            float Ysum = sh_vec[tid] + sh_vec[128+tid] + sh_vec[256+tid] + sh_vec[384+tid];
            float m1 = sh_red[18]*INV512;
            float r1 = rsqrtf(sh_red[19]*INV512 - m1*m1 + 1e-5f);
            int f = head*128 + tid;
            sh_q[tid] = r1*(Ysum - m1*sqg[f]) + cbqg[f];
          }
          __syncthreads();
#pragma unroll
          for (int rr = 0; rr < 32; ++rr) {
            unsigned pw = pj[rr];
            float sc = sh_q[lane]*bflo(pw) + sh_q[lane+64]*bfhi(pw);
            sc = wred(sc);
            if (lane == 0) sh_p[w*32+rr] = __expf(sc * QSCALE);
          }
          __syncthreads();
          {
            float acc = 0;
#pragma unroll
            for (int q = 0; q < 32; ++q) {
              unsigned pw = vv[q];
              acc += sh_p[g4*64 + 2*q]*bflo(pw) + sh_p[g4*64 + 2*q+1]*bfhi(pw);
            }
            sh_vec[tid] = acc;
          }
          if (w == 0) {
            float v = sh_p[lane] + sh_p[64+lane] + sh_p[128+lane] + sh_p[192+lane];
            v = wred(v);
            if (lane == 0) ast(denS + b, v);
          }
          __syncthreads();
          if (tid < 128) {
            float tot = sh_vec[tid] + sh_vec[128+tid] + sh_vec[256+tid] + sh_vec[384+tid];
            ast(CTXP + (size_t)b*128 + tid, tot);
          }
        } else if (ph5 == 3) {
          slotred32(s1s, sh_red, 18, w, lane);
          if (w == 4) {
            float v = (lane < 32) ? ald(denS + lane) : 0.f;
#pragma unroll
            for (int m = 4; m; m >>= 1) v += __shfl_xor(v, m);
            if ((lane & 7) == 0 && lane < 32) sh_den[lane >> 3] = v;
          }
          __syncthreads();
          {
            const int hh = tid >> 7;
            float cn = 0;
            float cv[8];
#pragma unroll
            for (int p = 0; p < 8; ++p) cv[p] = ald(CTXP + (size_t)(hh*8+p)*128 + dd);
#pragma unroll
            for (int p = 0; p < 8; ++p) cn += cv[p];
            sh_vec[tid] = cn / sh_den[hh];
          }
          __syncthreads();
          const float m1 = sh_red[18]*INV512;
          const float r1 = rsqrtf(sh_red[19]*INV512 - m1*m1 + 1e-5f);
#pragma unroll
          for (int rr = 0; rr < 2; ++rr) {
            const int r = w*2 + rr, j = b*16 + r;
            float a2 = 0;
#pragma unroll
            for (int kk = 0; kk < 4; ++kk) {
              unsigned pw = pj[rr*4+kk];
              a2 += bflo(pw)*sh_vec[lane+128*kk] + bfhi(pw)*sh_vec[lane+64+128*kk];
            }
            a2 = wred(a2);
            if (lane == 0) {
              float x1 = (sh_t1[r]-m1)*r1*lnG[(l*3)*HS + j] + lnB[(l*3)*HS + j];
              float t2v = x1 + a2 + caBo[l*HS + j];
              ast(t2g + j, t2v);
              sh_t2[r] = t2v;
            }
          }
          __syncthreads();
          if (w == 0 && lane < 16) {
            float v = sh_t2[lane], s_ = v, q_ = v*v;
#pragma unroll
            for (int m = 8; m; m >>= 1) { s_ += __shfl_xor(s_, m); q_ += __shfl_xor(q_, m); }
            if (lane == 0) { ast(s2s + b*2, s_); ast(s2s + b*2 + 1, q_); }
          }
        }
      } else if (!isA && t <= 127) {
        const int c = gb - 32;
        if (ph5 == 3) {
          // issue WGC at-use loads FIRST (independent of phase data)
          unsigned wg[32];
#pragma unroll
          for (int q = 0; q < 8; ++q) {
            const ushortt* b2 = WG + (size_t)(c*64 + w*8 + q)*HS;
#pragma unroll
            for (int kk = 0; kk < 4; ++kk)
              wg[q*4+kk] = ldpack(b2 + lane + 128*kk, b2 + lane + 64 + 128*kk);
          }
          float t1v = ald(t1g + tid);
          slotred32(s1s, sh_red, 18, w, lane);
          if (w == 4) {
            float v = (lane < 32) ? ald(denS + lane) : 0.f;
#pragma unroll
            for (int m = 4; m; m >>= 1) v += __shfl_xor(v, m);
            if ((lane & 7) == 0 && lane < 32) sh_den[lane >> 3] = v;
          }
          __syncthreads();
          {
            const float m1 = sh_red[18]*INV512;
            const float r1 = rsqrtf(sh_red[19]*INV512 - m1*m1 + 1e-5f);
            sh_xin[tid] = ((t1v - m1)*r1*lnG[(l*3)*HS + tid] + lnB[(l*3)*HS + tid])
                          * lnG[(l*3+1)*HS + tid];
          }
          {
            const int hh = tid >> 7;
            float cn = 0;
            float cv[8];
#pragma unroll
            for (int p = 0; p < 8; ++p) cv[p] = ald(CTXP + (size_t)(hh*8+p)*128 + dd);
#pragma unroll
            for (int p = 0; p < 8; ++p) cn += cv[p];
            sh_vec[tid] = cn / sh_den[hh];
          }
          __syncthreads();
#pragma unroll
          for (int q = 0; q < 8; ++q) {
            float acc = 0;
#pragma unroll
            for (int kk = 0; kk < 4; ++kk) {
              unsigned pw1 = pj[q*4+kk], pw2 = wg[q*4+kk];
              acc += bflo(pw1)*sh_xin[lane+128*kk] + bfhi(pw1)*sh_xin[lane+64+128*kk]
                   + bflo(pw2)*sh_vec[lane+128*kk] + bfhi(pw2)*sh_vec[lane+64+128*kk];
            }
            acc = wred(acc);
            if (lane == 0) sh_u[w*8+q] = acc;
          }
        } else if (ph5 == 4) {
          slotred32(s2s, sh_red, 16, w, lane);
          __syncthreads();
          const float m2 = sh_red[16]*INV512;
          const float r2 = rsqrtf(sh_red[17]*INV512 - m2*m2 + 1e-5f);
          if (lane == 0) {
#pragma unroll
            for (int q = 0; q < 8; ++q) {
              const int row = c*64 + w*8 + q;
              sh_ff[w*8+q] = fmaxf(r2*(sh_u[w*8+q] + cf1[row] - m2*suv[row]) + cf2[row], 0.f);
            }
          }
          __syncthreads();
          {
            float yl = 0;
#pragma unroll
            for (int q = 0; q < 32; ++q) {
              unsigned pw = pj[q];
              yl += sh_ff[2*q]*bflo(pw) + sh_ff[2*q+1]*bfhi(pw);
            }
            ast(Y2P + (size_t)c*HS + tid, yl);
          }
        }
      }
    }
    gridbar(bflags, (unsigned)(W+1), [&]{ pf(W+1); });
  }
}

// ---------------- host launcher ----------------
extern "C" void kernel_launch(void* const* d_in, const int* in_sizes, int n_in,
                              void* d_out, int out_size, void* d_ws, size_t ws_size,
                              hipStream_t stream) {
  const float* x      = (const float*)d_in[0];
  const float* hist   = (const float*)d_in[1];
  const float* Wx     = (const float*)d_in[2];
  const float* bx     = (const float*)d_in[3];
  const float* Wh     = (const float*)d_in[4];
  const float* bh     = (const float*)d_in[5];
  const float* saWin  = (const float*)d_in[6];
  const float* saBin  = (const float*)d_in[7];
  const float* saWo   = (const float*)d_in[8];
  const float* saBo   = (const float*)d_in[9];
  const float* caWin  = (const float*)d_in[10];
  const float* caBin  = (const float*)d_in[11];
  const float* caWo   = (const float*)d_in[12];
  const float* caBo   = (const float*)d_in[13];
  const float* ffW1   = (const float*)d_in[14];
  const float* ffB1   = (const float*)d_in[15];
  const float* ffW2   = (const float*)d_in[16];
  const float* ffB2   = (const float*)d_in[17];
  const float* lnG    = (const float*)d_in[18];
  const float* lnB    = (const float*)d_in[19];
  float* ws  = (float*)d_ws;
  float* out = (float*)d_out;

  hipMemsetAsync((char*)d_ws + OFF_STATE*sizeof(float), 0,
                 (WS_TOTAL - OFF_STATE)*sizeof(float), stream);

  kv_gemm<<<dim3(MMEM/64, HS/64, LNUM), 256, 0, stream>>>(
      hist, caWin, caBin, (ushortt*)(ws + OFF_KBF), HS);
  kv_gemm<<<dim3(MMEM/64, HS/64, LNUM), 256, 0, stream>>>(
      hist, caWin, caBin, (ushortt*)(ws + OFF_VBF), 2*HS);
  wcomb_gemm<<<dim3(HS/64, HS/64, LNUM), 256, 0, stream>>>(
      saWo, saWin, (ushortt*)(ws + OFF_WCOMBBF));
  wgc_gemm<<<dim3(FFD/64, HS/64, LNUM), 256, 0, stream>>>(
      ffW1, lnG, caWo, (ushortt*)(ws + OFF_WGCBF));
  csa_kernel<<<(LNUM*HS)/4, 256, 0, stream>>>(saWo, saBin, saBo, ws + OFF_CSA);
  transpose_scale_bf<<<dim3(HS/32, HS/32, LNUM), 256, 0, stream>>>(
      caWin, (size_t)(3*HS)*HS, HS, HS, lnG, (size_t)(3*HS),
      (ushortt*)(ws + OFF_WQTBF), (size_t)HS*HS);
  sqcbq_kernel<<<(LNUM*HS)/4, 256, 0, stream>>>(caWin, caBin, lnG, lnB, ws + OFF_SQ, ws + OFF_CBQ);
  transpose_scale_bf<<<dim3(FFD/32, HS/32, LNUM), 256, 0, stream>>>(
      ffW2, (size_t)HS*FFD, HS, FFD, nullptr, 0,
      (ushortt*)(ws + OFF_W2TBF), (size_t)FFD*HS);
  bf16_copy<<<2048, 256, 0, stream>>>(ffW1, (ushortt*)(ws + OFF_FFW1BF), (size_t)LNUM*FFD*HS);
  bf16_copy<<<1024, 256, 0, stream>>>(caWo, (ushortt*)(ws + OFF_CAWOBF), (size_t)LNUM*HS*HS);
  bf16_copy<<<2048, 256, 0, stream>>>(Wx, (ushortt*)(ws + OFF_WXBF), (size_t)LNUM*3*HS*HS);
  bf16_copy<<<2048, 256, 0, stream>>>(Wh, (ushortt*)(ws + OFF_WHBF), (size_t)LNUM*3*HS*HS);
  ffvec_kernel<<<(LNUM*FFD)/4, 256, 0, stream>>>(ffW1, ffB1, caBo, lnG, lnB,
      ws + OFF_SU, ws + OFF_CF1, ws + OFF_CF2);

  seq_kernel<<<NB, NT, 0, stream>>>(x, bx, bh, caBo, ffB2, lnG, lnB, ws, out);
}

// Round 12
// 11085.538 us; speedup vs baseline: 1.8669x; 1.8669x over previous
//
#include <hip/hip_runtime.h>

#define HS   512
#define LNUM 4
#define TT   128
#define MMEM 2048
#define FFD  2048
#define NB   256
#define NT   512
#define INV512 (1.0f/512.0f)
#define QSCALE 0.08838834764831845f  // 1/sqrt(128)

typedef unsigned short ushortt;

// ---------------- workspace layout (float offsets) ----------------
constexpr size_t KHALF = (size_t)LNUM*MMEM*HS/2;
constexpr size_t HHALF = (size_t)LNUM*HS*HS/2;
constexpr size_t FHALF = (size_t)LNUM*FFD*HS/2;
constexpr size_t OFF_KBF    = 0;
constexpr size_t OFF_VBF    = OFF_KBF    + KHALF;   // V stored TRANSPOSED [l][f][m]
constexpr size_t OFF_WCOMBBF= OFF_VBF    + KHALF;
constexpr size_t OFF_WQP    = OFF_WCOMBBF+ HHALF;   // packed [l][b][f][16]
constexpr size_t OFF_W2P    = OFF_WQP    + HHALF;   // packed [l][bid][f][8]
constexpr size_t OFF_FFW1BF = OFF_W2P    + FHALF;
constexpr size_t OFF_CAWOBF = OFF_FFW1BF + FHALF;
constexpr size_t OFF_CSA    = OFF_CAWOBF + HHALF;                 // L*HS
constexpr size_t OFF_SQ     = OFF_CSA    + (size_t)LNUM*HS;
constexpr size_t OFF_CBQ    = OFF_SQ     + (size_t)LNUM*HS;
// mutable (memset 0)
constexpr size_t OFF_STATE = OFF_CBQ   + (size_t)LNUM*HS;
constexpr size_t OFF_H     = OFF_STATE;                           // [2][4][512]
constexpr size_t OFF_C     = OFF_H     + 2*LNUM*HS;
constexpr size_t OFF_XING  = OFF_C     + 2*LNUM*HS;               // 512
constexpr size_t OFF_Z1    = OFF_XING  + HS;                      // 512
constexpr size_t OFF_Z02   = OFF_Z1    + HS;                      // 1024
constexpr size_t OFF_T2G   = OFF_Z02   + 2*HS;                    // 512
constexpr size_t OFF_YP    = OFF_T2G   + HS;                      // 4*HS planes
constexpr size_t OFF_Y2P   = OFF_YP    + 4*HS;                    // 8*HS planes
constexpr size_t OFF_CTXP  = OFF_Y2P   + 8*HS;                    // 8*HS planes
constexpr size_t OFF_DENS  = OFF_CTXP  + 8*HS;                    // 128 slots
constexpr size_t OFF_S1S   = OFF_DENS  + 128;                     // 32*2 slots
constexpr size_t OFF_S2S   = OFF_S1S   + 64;                      // 32*2 slots
constexpr size_t OFF_J1    = OFF_S2S   + 64;                      // 65*32 u32
constexpr size_t OFF_J2    = OFF_J1    + 65*32;                   // 128*32 u32
constexpr size_t OFF_FLAGS = OFF_J2    + 128*32;                  // NB*32 u32
constexpr size_t WS_TOTAL  = OFF_FLAGS + (size_t)NB*32;

__device__ __forceinline__ float wred(float v) {
#pragma unroll
  for (int m = 32; m; m >>= 1) v += __shfl_xor(v, m);
  return v;
}
__device__ __forceinline__ float sigm(float x) { return 1.0f/(1.0f+__expf(-x)); }
__device__ __forceinline__ ushortt f2bf(float f) {
  unsigned u = __float_as_uint(f);
  return (ushortt)((u + 0x7fffu + ((u >> 16) & 1u)) >> 16);
}
__device__ __forceinline__ float bflo(unsigned v){ return __uint_as_float(v << 16); }
__device__ __forceinline__ float bfhi(unsigned v){ return __uint_as_float(v & 0xffff0000u); }
// 8 bf16 (16B) -> 4 packed u32
__device__ __forceinline__ void ld8bfp(const ushortt* p, unsigned* d) {
  uint4 v = *(const uint4*)p;
  d[0] = v.x; d[1] = v.y; d[2] = v.z; d[3] = v.w;
}
// 8 f32 (32B) -> 8 floats via 2x float4
__device__ __forceinline__ void ld8f(const float* p, float* d) {
  float4 a = *(const float4*)p, b = *(const float4*)(p + 4);
  d[0]=a.x; d[1]=a.y; d[2]=a.z; d[3]=a.w; d[4]=b.x; d[5]=b.y; d[6]=b.z; d[7]=b.w;
}

__device__ __forceinline__ float ald(const float* p) {
  return __hip_atomic_load(p, __ATOMIC_RELAXED, __HIP_MEMORY_SCOPE_AGENT);
}
__device__ __forceinline__ void ast(float* p, float v) {
  __hip_atomic_store(p, v, __ATOMIC_RELAXED, __HIP_MEMORY_SCOPE_AGENT);
}
__device__ __forceinline__ unsigned aldu(const unsigned* p) {
  return __hip_atomic_load(p, __ATOMIC_RELAXED, __HIP_MEMORY_SCOPE_AGENT);
}
__device__ __forceinline__ void astu(unsigned* p, unsigned v) {
  __hip_atomic_store(p, v, __ATOMIC_RELAXED, __HIP_MEMORY_SCOPE_AGENT);
}

// direct-poll grid barrier with prefetch hook (R6-proven)
template <class F>
__device__ __forceinline__ void barrier_pf(unsigned* flags, unsigned g, F&& pf) {
  asm volatile("s_waitcnt vmcnt(0)" ::: "memory");
  __syncthreads();
  if (threadIdx.x == 0) astu(flags + (size_t)blockIdx.x*32, g);
  pf();
  if (threadIdx.x < NB) {
    const unsigned* f = flags + (size_t)threadIdx.x*32;
    while ((int)(aldu(f) - g) < 0) __builtin_amdgcn_s_sleep(2);
  }
  __syncthreads();
}
__device__ __forceinline__ void jflag(unsigned* J, int id, unsigned val) {
  asm volatile("s_waitcnt vmcnt(0)" ::: "memory");
  __syncthreads();
  if (threadIdx.x == 0) astu(J + (size_t)id*32, val);
}
template <class F>
__device__ __forceinline__ void jwait_pf(unsigned* J, int n, unsigned val, F&& pf) {
  pf();
  if (threadIdx.x < n) {
    const unsigned* f = J + (size_t)threadIdx.x*32;
    while ((int)(aldu(f) - val) < 0) __builtin_amdgcn_s_sleep(1);
  }
  __syncthreads();
}
__device__ __forceinline__ void slotred32(const float* slots, float* sh, int o,
                                          int w, int lane) {
  if (w == 0) {
    float a = (lane < 32) ? ald(slots + lane*2) : ald(slots + (lane-32)*2 + 1);
#pragma unroll
    for (int m = 16; m; m >>= 1) a += __shfl_xor(a, m);
    if (lane == 0)  sh[o]   = a;
    if (lane == 32) sh[o+1] = a;
  }
}

// ---------------- precompute kernels ----------------

// vt=0: row-major [l][m][f]; vt=1: transposed [l][f][m]
__global__ __launch_bounds__(256) void kv_gemm(
    const float* __restrict__ hist, const float* __restrict__ caWin,
    const float* __restrict__ caBin, ushortt* __restrict__ out, int koff, int vt) {
  __shared__ float As[16][64];
  __shared__ float Bs[16][64];
  const int l = blockIdx.z, m0 = blockIdx.x*64, f0 = blockIdx.y*64;
  const int tid = threadIdx.x, tm = tid >> 4, tf = tid & 15;
  float acc[4][4] = {};
  for (int e0 = 0; e0 < HS; e0 += 16) {
#pragma unroll
    for (int it = 0; it < 4; ++it) {
      int idx = tid + it*256, k = idx & 15, mm = idx >> 4;
      As[k][mm] = hist[((size_t)(m0+mm)*LNUM + l)*HS + e0 + k];
      Bs[k][mm] = caWin[((size_t)l*(3*HS) + koff + f0 + mm)*HS + e0 + k];
    }
    __syncthreads();
#pragma unroll
    for (int k = 0; k < 16; ++k) {
      float a[4], b[4];
#pragma unroll
      for (int xx = 0; xx < 4; ++xx) { a[xx] = As[k][tm*4+xx]; b[xx] = Bs[k][tf*4+xx]; }
#pragma unroll
      for (int xx = 0; xx < 4; ++xx)
#pragma unroll
        for (int y = 0; y < 4; ++y) acc[xx][y] += a[xx]*b[y];
    }
    __syncthreads();
  }
#pragma unroll
  for (int xx = 0; xx < 4; ++xx)
#pragma unroll
    for (int y = 0; y < 4; ++y) {
      int m = m0 + tm*4 + xx, f = f0 + tf*4 + y;
      ushortt v = f2bf(acc[xx][y] + caBin[l*(3*HS) + koff + f]);
      if (vt) out[(size_t)l*MMEM*HS + (size_t)f*MMEM + m] = v;
      else    out[((size_t)l*MMEM + m)*HS + f] = v;
    }
}

__global__ __launch_bounds__(256) void wcomb_gemm(
    const float* __restrict__ saWo, const float* __restrict__ saWin,
    ushortt* __restrict__ wcomb) {
  __shared__ float As[16][64];
  __shared__ float Bs[16][64];
  const int l = blockIdx.z, f0 = blockIdx.x*64, j0 = blockIdx.y*64;
  const int tid = threadIdx.x, tm = tid >> 4, tf = tid & 15;
  float acc[4][4] = {};
  for (int e0 = 0; e0 < HS; e0 += 16) {
#pragma unroll
    for (int it = 0; it < 4; ++it) {
      int idx = tid + it*256;
      { int k = idx & 15, ff = idx >> 4;
        As[k][ff] = saWo[((size_t)l*HS + f0+ff)*HS + e0 + k]; }
      { int jj = idx & 63, k = idx >> 6;
        Bs[k][jj] = saWin[((size_t)l*(3*HS) + 2*HS + e0 + k)*HS + j0 + jj]; }
    }
    __syncthreads();
#pragma unroll
    for (int k = 0; k < 16; ++k) {
      float a[4], b[4];
#pragma unroll
      for (int xx = 0; xx < 4; ++xx) { a[xx] = As[k][tm*4+xx]; b[xx] = Bs[k][tf*4+xx]; }
#pragma unroll
      for (int xx = 0; xx < 4; ++xx)
#pragma unroll
        for (int y = 0; y < 4; ++y) acc[xx][y] += a[xx]*b[y];
    }
    __syncthreads();
  }
#pragma unroll
  for (int xx = 0; xx < 4; ++xx)
#pragma unroll
    for (int y = 0; y < 4; ++y)
      wcomb[(size_t)l*HS*HS + (size_t)(f0+tm*4+xx)*HS + (j0+tf*4+y)] = f2bf(acc[xx][y]);
}

// WQP[l][b][f][16]: r-th = caWin[l][f][b*16+r] * g1[b*16+r]
__global__ __launch_bounds__(256) void pack_wq(
    const float* __restrict__ caWin, const float* __restrict__ lnG,
    ushortt* __restrict__ wqp) {
  const int b = blockIdx.x, l = blockIdx.y;
  for (int idx = threadIdx.x; idx < 512*16; idx += 256) {
    int f = idx >> 4, r = idx & 15, j = b*16 + r;
    wqp[(((size_t)l*32 + b)*512 + f)*16 + r] =
        f2bf(caWin[((size_t)l*3*HS + f)*HS + j] * lnG[l*3*HS + j]);
  }
}

// W2P[l][bid][f][8]: r-th = ffW2[l][f][bid*8+r]
__global__ __launch_bounds__(256) void pack_w2(
    const float* __restrict__ ffW2, ushortt* __restrict__ w2p) {
  const int bid = blockIdx.x, l = blockIdx.y;
  for (int idx = threadIdx.x; idx < 512*8; idx += 256) {
    int f = idx >> 3, r = idx & 7;
    w2p[(((size_t)l*NB + bid)*512 + f)*8 + r] =
        f2bf(ffW2[((size_t)l*HS + f)*FFD + bid*8 + r]);
  }
}

__global__ __launch_bounds__(256) void bf16_copy(
    const float* __restrict__ in, ushortt* __restrict__ out, size_t n) {
  for (size_t i = (size_t)blockIdx.x*256 + threadIdx.x; i < n; i += (size_t)gridDim.x*256)
    out[i] = f2bf(in[i]);
}

__global__ __launch_bounds__(256) void csa_kernel(
    const float* __restrict__ saWo, const float* __restrict__ sabin,
    const float* __restrict__ sabo, float* __restrict__ csa) {
  const int w = threadIdx.x >> 6, lane = threadIdx.x & 63;
  const int row = blockIdx.x*4 + w;
  const int l = row >> 9, f = row & 511;
  float acc = 0;
#pragma unroll
  for (int k = 0; k < 8; ++k) {
    int e = lane + 64*k;
    acc += saWo[((size_t)l*HS + f)*HS + e] * sabin[l*(3*HS) + 2*HS + e];
  }
  acc = wred(acc);
  if (lane == 0) csa[row] = acc + sabo[l*HS + f];
}

__global__ __launch_bounds__(256) void sqcbq_kernel(
    const float* __restrict__ caWin, const float* __restrict__ caBin,
    const float* __restrict__ lnG, const float* __restrict__ lnB,
    float* __restrict__ sq, float* __restrict__ cbq) {
  const int w = threadIdx.x >> 6, lane = threadIdx.x & 63;
  const int row = blockIdx.x*4 + w;
  const int l = row >> 9, f = row & 511;
  float a1 = 0, a2 = 0;
#pragma unroll
  for (int k = 0; k < 8; ++k) {
    int e = lane + 64*k;
    float wv = caWin[((size_t)l*(3*HS) + f)*HS + e];
    a1 += wv * lnG[l*(3*HS) + e];
    a2 += wv * lnB[l*(3*HS) + e];
  }
  a1 = wred(a1); a2 = wred(a2);
  if (lane == 0) { sq[row] = a1; cbq[row] = a2 + caBin[l*(3*HS) + f]; }
}

// ---------------- main persistent sequential kernel (R6 topology) ----------------

__global__ __launch_bounds__(NT, 1) void seq_kernel(
    const float* __restrict__ x,
    const float* __restrict__ Wx,  const float* __restrict__ bx,
    const float* __restrict__ Wh,  const float* __restrict__ bh,
    const float* __restrict__ caBo,
    const float* __restrict__ ffB1,
    const float* __restrict__ ffB2,
    const float* __restrict__ lnG,  const float* __restrict__ lnB,
    float* __restrict__ ws, float* __restrict__ out) {
  const ushortt* Kb    = (const ushortt*)(ws + OFF_KBF);
  const ushortt* Vt    = (const ushortt*)(ws + OFF_VBF);   // [l][f][m]
  const ushortt* Wcomb = (const ushortt*)(ws + OFF_WCOMBBF);
  const ushortt* WQP   = (const ushortt*)(ws + OFF_WQP);
  const ushortt* W2P   = (const ushortt*)(ws + OFF_W2P);
  const ushortt* F1b   = (const ushortt*)(ws + OFF_FFW1BF);
  const ushortt* CaWob = (const ushortt*)(ws + OFF_CAWOBF);
  const float* csag  = ws + OFF_CSA;
  const float* sqg   = ws + OFF_SQ;
  const float* cbqg  = ws + OFF_CBQ;
  float* hG    = ws + OFF_H;
  float* cG    = ws + OFF_C;
  float* xing  = ws + OFF_XING;
  float* z1g   = ws + OFF_Z1;
  float* z02g  = ws + OFF_Z02;
  float* t2g   = ws + OFF_T2G;
  float* Yp    = ws + OFF_YP;
  float* Y2p   = ws + OFF_Y2P;
  float* ctxP  = ws + OFF_CTXP;
  float* denS  = ws + OFF_DENS;
  float* s1s   = ws + OFF_S1S;
  float* s2s   = ws + OFF_S2S;
  unsigned* J1     = (unsigned*)(ws + OFF_J1);
  unsigned* J2     = (unsigned*)(ws + OFF_J2);
  unsigned* bflags = (unsigned*)(ws + OFF_FLAGS);

  __shared__ float sh_xin[HS], sh_h[HS], sh_vec[HS], sh_aux[HS];
  __shared__ float sh_q[128], sh_p[64], sh_t1[16];
  __shared__ float sh_red[24], sh_den[4];

  const int bid = blockIdx.x, tid = threadIdx.x;
  const int w = tid >> 6, lane = tid & 63;
  unsigned gen = 1;

  // prefetch registers: f32 gate rows as floats; bf16 rows as packed u32 (4/row)
  float    pZx[8],  pZh[8];       // z1 rows (bid<64)
  float    pZx2[8], pZh2[8];      // z0/z2 rows (bid<32 | bid>=160)
  unsigned pWc[2][4], pWq[8];     // H2 (bid<32)
  unsigned pK[2][4],  pV[8];      // H3 attn (32<=bid<160)
  unsigned pCa[2][4];             // H4 (bid<32)
  unsigned pF1[4], pW2[4];        // H5 (all)

  auto pfH1 = [&](int l) {
    if (bid < 64) {
      const size_t ro = (((size_t)l*3 + 1)*HS + bid*8 + w)*HS + lane*8;
      ld8f(Wx + ro, pZx);
      ld8f(Wh + ro, pZh);
    }
  };
  auto pfH2 = [&](int l) {
    if (bid < 32) {
#pragma unroll
      for (int rr = 0; rr < 2; ++rr)
        ld8bfp(Wcomb + ((size_t)l*HS + bid*16 + w*2 + rr)*HS + lane*8, pWc[rr]);
      const ushortt* q = WQP + (((size_t)l*32 + bid)*512 + tid)*16;
      ld8bfp(q,     pWq);
      ld8bfp(q + 8, pWq + 4);
    }
  };
  auto pfH3 = [&](int l) {
    if (bid >= 32 && bid < 160) {
      const int b2 = bid - 32, h = b2 >> 5, ms = b2 & 31;
#pragma unroll
      for (int rr = 0; rr < 2; ++rr)
        ld8bfp(Kb + ((size_t)l*MMEM + ms*64 + w*8 + (lane>>4) + 4*rr)*HS
                  + h*128 + (lane & 15)*8, pK[rr]);
      const ushortt* vp = Vt + (size_t)l*MMEM*HS
                        + ((size_t)h*128 + (tid & 127))*MMEM + ms*64 + (tid >> 7)*16;
      ld8bfp(vp,     pV);
      ld8bfp(vp + 8, pV + 4);
    }
  };
  auto pfZ = [&](int l) {
    if (bid < 32 || bid >= 160) {
      const int zb = (bid < 32) ? bid : bid - 128;
      const int rowid = zb*8 + w;
      const int g = (rowid < 512) ? 0 : 2;
      const int f = rowid & 511;
      const size_t ro = (((size_t)l*3 + g)*HS + f)*HS + lane*8;
      ld8f(Wx + ro, pZx2);
      ld8f(Wh + ro, pZh2);
    }
  };
  auto pfH4 = [&](int l) {
    if (bid < 32) {
#pragma unroll
      for (int rr = 0; rr < 2; ++rr)
        ld8bfp(CaWob + ((size_t)l*HS + bid*16 + w*2 + rr)*HS + lane*8, pCa[rr]);
    }
  };
  auto pfH5 = [&](int l) {
    ld8bfp(F1b + ((size_t)l*FFD + bid*8 + w)*HS + lane*8, pF1);
    ld8bfp(W2P + (((size_t)l*NB + bid)*512 + tid)*8, pW2);
  };

  auto do_update = [&](int ip, int parp, float& xn, float& cn) {
    const int j = tid;
    float t2v = ald(t2g + j);
    float z0  = ald(z02g + j);
    float z2  = ald(z02g + HS + j);
    float y2 = 0;
    {
      float yv[8];
#pragma unroll
      for (int p = 0; p < 8; ++p) yv[p] = ald(Y2p + (size_t)p*HS + j);
#pragma unroll
      for (int p = 0; p < 8; ++p) y2 += yv[p];
    }
    slotred32(s2s, sh_red, 16, w, lane);
    __syncthreads();
    float m2 = sh_red[16]*INV512;
    float r2 = rsqrtf(sh_red[17]*INV512 - m2*m2 + 1e-5f);
    float x2 = (t2v-m2)*r2*lnG[(ip*3+1)*HS+j] + lnB[(ip*3+1)*HS+j];
    float t3 = x2 + y2 + ffB2[ip*HS + j];
    float s_ = t3, q_ = t3*t3;
#pragma unroll
    for (int m = 32; m; m >>= 1) { s_ += __shfl_xor(s_, m); q_ += __shfl_xor(q_, m); }
    if (lane == 0) { sh_red[w] = s_; sh_red[8+w] = q_; }
    __syncthreads();
    if (tid == 0) {
      float a = 0, b = 0;
#pragma unroll
      for (int k = 0; k < 8; ++k) { a += sh_red[k]; b += sh_red[8+k]; }
      sh_red[0] = a; sh_red[1] = b;
    }
    __syncthreads();
    float m3 = sh_red[0]*INV512;
    float r3 = rsqrtf(sh_red[1]*INV512 - m3*m3 + 1e-5f);
    float d  = (t3-m3)*r3*lnG[(ip*3+2)*HS+j] + lnB[(ip*3+2)*HS+j];
    float cp = ald(cG + (parp*LNUM + ip)*HS + j);
    float ft = sigm(cp - d);
    float it = sigm(z0);
    float gt = tanhf(z2);
    cn = ft*cp + it*gt;
    xn = tanhf(cn);
  };

  pfH1(0); pfH2(0); pfH3(0);

  for (int s = 0; s < TT*LNUM; ++s) {
    const int t = s >> 2, i = s & 3;
    const int par = t & 1;
    const unsigned jv = (unsigned)(s + 1);
    // ---------- H1 window: update(s-1) + z1 matvec (0-63); zeroers (64-66) ----------
    if (bid < 64) {
      float xn = 0.f, cn = 0.f;
      if (s > 0) {
        const int ip = (s-1) & 3, tp = (s-1) >> 2, parp = tp & 1;
        if (bid == 0 || i > 0) {
          do_update(ip, parp, xn, cn);
          if (bid == 0) {
            ast(hG + ((parp^1)*LNUM + ip)*HS + tid, xn);
            ast(cG + ((parp^1)*LNUM + ip)*HS + tid, cn);
            if (ip == 3) out[tp*HS + tid] = xn;
          }
        }
      }
      float xv = (i == 0) ? x[t*HS + tid] : xn;
      sh_xin[tid] = xv;
      sh_h[tid]   = ald(hG + (par*LNUM + i)*HS + tid);
      if (bid == 0) ast(xing + tid, xv);
      __syncthreads();
      const int f = bid*8 + w;
      float acc = 0;
#pragma unroll
      for (int m = 0; m < 8; ++m)
        acc += pZx[m]*sh_xin[lane*8+m] + pZh[m]*sh_h[lane*8+m];
      acc = wred(acc);
      if (lane == 0) ast(z1g + f, acc + bx[(i*3+1)*HS + f] + bh[(i*3+1)*HS + f]);
      jflag(J1, bid, jv);
    } else if (bid == 64) {
#pragma unroll
      for (int p = 0; p < 4; ++p) ast(Yp + (size_t)p*HS + tid, 0.f);
      jflag(J1, 64, jv);
    } else if (bid == 65) {
#pragma unroll
      for (int p = 0; p < 8; ++p) ast(ctxP + (size_t)p*HS + tid, 0.f);
    } else if (bid == 66) {
      jwait_pf(J1, 65, jv, [&]{});
#pragma unroll
      for (int p = 0; p < 8; ++p) ast(Y2p + (size_t)p*HS + tid, 0.f);
    }
    // ---------- J1 -> H2 (blocks 0-31): t1 + deferred q + stats1 slots ----------
    if (bid < 32) {
      jwait_pf(J1, 65, jv, [&]{});
      sh_vec[tid] = sigm(ald(z1g + tid));  // f0
      __syncthreads();
#pragma unroll
      for (int rr = 0; rr < 2; ++rr) {
        const int r = w*2 + rr, j = bid*16 + r;
        float acc = 0;
#pragma unroll
        for (int k = 0; k < 4; ++k) {
          unsigned pw = pWc[rr][k];
          acc += bflo(pw)*sh_vec[lane*8 + 2*k] + bfhi(pw)*sh_vec[lane*8 + 2*k + 1];
        }
        acc = wred(acc);
        if (lane == 0) {
          float t1v = sh_vec[j] + acc + csag[i*HS + j];
          sh_t1[r]  = t1v;
          sh_aux[r] = t1v;
        }
      }
      __syncthreads();
      {
        float yl = 0;
#pragma unroll
        for (int q = 0; q < 8; ++q) {
          unsigned pw = pWq[q];
          yl += sh_aux[2*q]*bflo(pw) + sh_aux[2*q+1]*bfhi(pw);
        }
        atomicAdd(&Yp[(size_t)(bid & 3)*HS + tid], yl);
      }
      if (w == 0 && lane < 16) {
        float v = sh_aux[lane], s_ = v, q_ = v*v;
#pragma unroll
        for (int m = 8; m; m >>= 1) { s_ += __shfl_xor(s_, m); q_ += __shfl_xor(q_, m); }
        if (lane == 0) { ast(s1s + bid*2, s_); ast(s1s + bid*2 + 1, q_); }
      }
    }
    barrier_pf(bflags, gen, [&]{ pfZ(i); pfH4(i); pfH5(i); });
    // ---------- H3 window: attention (32-159) | z0/z2 (0-31, 160-255) ----------
    if (bid >= 32 && bid < 160) {
      const int b2 = bid - 32, h = b2 >> 5;
      slotred32(s1s, sh_red, 18, w, lane);
      __syncthreads();
      if (tid < 128) {
        float m1 = sh_red[18]*INV512;
        float r1 = rsqrtf(sh_red[19]*INV512 - m1*m1 + 1e-5f);
        int f = h*128 + tid;
        float Ysum = 0;
#pragma unroll
        for (int p = 0; p < 4; ++p) Ysum += ald(Yp + (size_t)p*HS + f);
        sh_q[tid] = r1*(Ysum - m1*sqg[i*HS + f]) + cbqg[i*HS + f];
      }
      __syncthreads();
      // scores: 16-lane groups, 4 rows per instruction, 2 iterations
#pragma unroll
      for (int rr = 0; rr < 2; ++rr) {
        float sc = 0;
#pragma unroll
        for (int k = 0; k < 4; ++k) {
          unsigned pw = pK[rr][k];
          sc += bflo(pw)*sh_q[(lane & 15)*8 + 2*k] + bfhi(pw)*sh_q[(lane & 15)*8 + 2*k + 1];
        }
#pragma unroll
        for (int msk = 8; msk; msk >>= 1) sc += __shfl_xor(sc, msk);
        if ((lane & 15) == 0) sh_p[w*8 + (lane >> 4) + 4*rr] = __expf(sc * QSCALE);
      }
      __syncthreads();
      {   // ctx partial (Vt: 16 contiguous m per thread)
        const int d = tid & 127, mg = tid >> 7;
        float acc = 0;
#pragma unroll
        for (int q = 0; q < 8; ++q) {
          unsigned pw = pV[q];
          acc += sh_p[mg*16 + 2*q]*bflo(pw) + sh_p[mg*16 + 2*q + 1]*bfhi(pw);
        }
        atomicAdd(&ctxP[(size_t)((b2 & 1)*4 + mg)*HS + h*128 + d], acc);
      }
      if (w == 0) {
        float v = wred(sh_p[lane]);
        if (lane == 0) ast(denS + h*32 + (b2 & 31), v);
      }
      jflag(J2, b2, jv);
    } else {
      const int zb = (bid < 32) ? bid : bid - 128;
      if (bid >= 160) {
        sh_xin[tid] = ald(xing + tid);
        sh_h[tid]   = ald(hG + (par*LNUM + i)*HS + tid);
      }
      __syncthreads();
      const int rowid = zb*8 + w;
      const int g = (rowid < 512) ? 0 : 2;
      const int f = rowid & 511;
      float acc = 0;
#pragma unroll
      for (int m = 0; m < 8; ++m)
        acc += pZx2[m]*sh_xin[lane*8+m] + pZh2[m]*sh_h[lane*8+m];
      acc = wred(acc);
      if (lane == 0) ast(z02g + (g ? HS : 0) + f, acc + bx[(i*3+g)*HS + f] + bh[(i*3+g)*HS + f]);
      // ---------- J2 -> H4 (blocks 0-31): t2 + stats2 slots ----------
      if (bid < 32) {
        jwait_pf(J2, 128, jv, [&]{});
        slotred32(s1s, sh_red, 18, w, lane);
        if (w >= 4) {
          float v = (lane < 32) ? ald(denS + (w-4)*32 + lane) : 0.f;
#pragma unroll
          for (int m = 16; m; m >>= 1) v += __shfl_xor(v, m);
          if (lane == 0) sh_den[w-4] = v;
        }
        __syncthreads();
        const float m1 = sh_red[18]*INV512;
        const float r1 = rsqrtf(sh_red[19]*INV512 - m1*m1 + 1e-5f);
        {
          float c = 0;
#pragma unroll
          for (int p = 0; p < 8; ++p) c += ald(ctxP + (size_t)p*HS + tid);
          sh_vec[tid] = c / sh_den[tid >> 7];
        }
        __syncthreads();
#pragma unroll
        for (int rr = 0; rr < 2; ++rr) {
          const int r = w*2 + rr, j = bid*16 + r;
          float a2 = 0;
#pragma unroll
          for (int k = 0; k < 4; ++k) {
            unsigned pw = pCa[rr][k];
            a2 += bflo(pw)*sh_vec[lane*8 + 2*k] + bfhi(pw)*sh_vec[lane*8 + 2*k + 1];
          }
          a2 = wred(a2);
          if (lane == 0) {
            float x1 = (sh_t1[r]-m1)*r1*lnG[(i*3)*HS + j] + lnB[(i*3)*HS + j];
            float t2v = x1 + a2 + caBo[i*HS + j];
            ast(t2g + j, t2v);
            sh_aux[r] = t2v;
          }
        }
        __syncthreads();
        if (w == 0 && lane < 16) {
          float v = sh_aux[lane], s_ = v, q_ = v*v;
#pragma unroll
          for (int m = 8; m; m >>= 1) { s_ += __shfl_xor(s_, m); q_ += __shfl_xor(q_, m); }
          if (lane == 0) { ast(s2s + bid*2, s_); ast(s2s + bid*2 + 1, q_); }
        }
      }
    }
    barrier_pf(bflags, gen+1, [&]{ const int nl = (s+1) & 3; pfH1(nl); pfH2(nl); pfH3(nl); });
    // ---------- H5: all blocks: ff1 = relu(W1@x2+b1); Y2 plane += W2T@ff1 ----------
    {
      slotred32(s2s, sh_red, 16, w, lane);
      __syncthreads();
      const float m2 = sh_red[16]*INV512;
      const float r2 = rsqrtf(sh_red[17]*INV512 - m2*m2 + 1e-5f);
      sh_vec[tid] = (ald(t2g + tid)-m2)*r2*lnG[(i*3+1)*HS + tid] + lnB[(i*3+1)*HS + tid];
      __syncthreads();
      const int kk = bid*8 + w;
      float acc = 0;
#pragma unroll
      for (int k = 0; k < 4; ++k) {
        unsigned pw = pF1[k];
        acc += bflo(pw)*sh_vec[lane*8 + 2*k] + bfhi(pw)*sh_vec[lane*8 + 2*k + 1];
      }
      acc = wred(acc);
      if (lane == 0) sh_aux[w] = fmaxf(acc + ffB1[i*FFD + kk], 0.f);
      __syncthreads();
      float yl = 0;
#pragma unroll
      for (int q = 0; q < 4; ++q) {
        unsigned pw = pW2[q];
        yl += sh_aux[2*q]*bflo(pw) + sh_aux[2*q+1]*bfhi(pw);
      }
      atomicAdd(&Y2p[(size_t)(bid & 7)*HS + tid], yl);
    }
    barrier_pf(bflags, gen+2, [&]{});
    gen += 3;
  }

  // ---------- epilogue: final update (t=127, i=3) + output assembly ----------
  if (bid == 0) {
    float xn, cn;
    do_update(3, 1, xn, cn);
    out[127*HS + tid] = xn;
    out[TT*HS + 3*HS + tid] = xn;                 // h_T[3]
    out[TT*HS + LNUM*HS + 3*HS + tid] = cn;       // c_T[3]
#pragma unroll
    for (int ii = 0; ii < 3; ++ii) {
      out[TT*HS + ii*HS + tid]            = ald(hG + (0*LNUM + ii)*HS + tid);
      out[TT*HS + LNUM*HS + ii*HS + tid]  = ald(cG + (0*LNUM + ii)*HS + tid);
    }
  }
}

// ---------------- host launcher ----------------
extern "C" void kernel_launch(void* const* d_in, const int* in_sizes, int n_in,
                              void* d_out, int out_size, void* d_ws, size_t ws_size,
                              hipStream_t stream) {
  const float* x      = (const float*)d_in[0];
  const float* hist   = (const float*)d_in[1];
  const float* Wx     = (const float*)d_in[2];
  const float* bx     = (const float*)d_in[3];
  const float* Wh     = (const float*)d_in[4];
  const float* bh     = (const float*)d_in[5];
  const float* saWin  = (const float*)d_in[6];
  const float* saBin  = (const float*)d_in[7];
  const float* saWo   = (const float*)d_in[8];
  const float* saBo   = (const float*)d_in[9];
  const float* caWin  = (const float*)d_in[10];
  const float* caBin  = (const float*)d_in[11];
  const float* caWo   = (const float*)d_in[12];
  const float* caBo   = (const float*)d_in[13];
  const float* ffW1   = (const float*)d_in[14];
  const float* ffB1   = (const float*)d_in[15];
  const float* ffW2   = (const float*)d_in[16];
  const float* ffB2   = (const float*)d_in[17];
  const float* lnG    = (const float*)d_in[18];
  const float* lnB    = (const float*)d_in[19];
  float* ws  = (float*)d_ws;
  float* out = (float*)d_out;

  hipMemsetAsync((char*)d_ws + OFF_STATE*sizeof(float), 0,
                 (WS_TOTAL - OFF_STATE)*sizeof(float), stream);

  kv_gemm<<<dim3(MMEM/64, HS/64, LNUM), 256, 0, stream>>>(
      hist, caWin, caBin, (ushortt*)(ws + OFF_KBF), HS, 0);
  kv_gemm<<<dim3(MMEM/64, HS/64, LNUM), 256, 0, stream>>>(
      hist, caWin, caBin, (ushortt*)(ws + OFF_VBF), 2*HS, 1);   // V transposed
  wcomb_gemm<<<dim3(HS/64, HS/64, LNUM), 256, 0, stream>>>(
      saWo, saWin, (ushortt*)(ws + OFF_WCOMBBF));
  csa_kernel<<<(LNUM*HS)/4, 256, 0, stream>>>(saWo, saBin, saBo, ws + OFF_CSA);
  pack_wq<<<dim3(32, LNUM), 256, 0, stream>>>(caWin, lnG, (ushortt*)(ws + OFF_WQP));
  sqcbq_kernel<<<(LNUM*HS)/4, 256, 0, stream>>>(caWin, caBin, lnG, lnB, ws + OFF_SQ, ws + OFF_CBQ);
  pack_w2<<<dim3(NB, LNUM), 256, 0, stream>>>(ffW2, (ushortt*)(ws + OFF_W2P));
  bf16_copy<<<2048, 256, 0, stream>>>(ffW1, (ushortt*)(ws + OFF_FFW1BF), (size_t)LNUM*FFD*HS);
  bf16_copy<<<1024, 256, 0, stream>>>(caWo, (ushortt*)(ws + OFF_CAWOBF), (size_t)LNUM*HS*HS);

  seq_kernel<<<NB, NT, 0, stream>>>(x, Wx, bx, Wh, bh, caBo,
                                    ffB1, ffB2, lnG, lnB, ws, out);
}